// Round 4
// baseline (546.500 us; speedup 1.0000x reference)
//
#include <hip/hip_runtime.h>
#include <hip/hip_bf16.h>
#include <stdint.h>

// LSTM cell: gates = [X|h0](16384x2048) @ Bt^T(2048x4096), fused epilogue.
// bf16 MFMA 16x16x32, 256x256 tile, 8 waves, BK=32, 4-deep LDS slots.
// R2: register-level fragment double-buffer. During tile t's MFMA burst the
// wave reads tile t+1's frags into the alternate register set, so the MFMA
// burst has NO lgkmcnt dependency on just-issued ds_reads -> LDS pipe
// (~1152cyc/CU/tile) and matrix pipe (~1242cyc) co-run. Prefetch distance 3
// (stage t+3 during t, vmcnt(4) forces t+2 landed at end of t).
// Gate-interleaved p-space so acc[mi][0..3] = gates i,f,g,o of ONE output
// column in the SAME lane -> epilogue is pure register math.

typedef __bf16 bf16x8 __attribute__((ext_vector_type(8)));
typedef float f32x4 __attribute__((ext_vector_type(4)));

#define B_ROWS 16384
#define KDIM 2048
#define DH 1024
#define HC_ELEMS 16777216ull  // 16384*1024
#define NT 64                 // K-tiles of BK=32

__device__ __forceinline__ unsigned short f2bf(float f) {
  unsigned u = __float_as_uint(f);
  u = (u + 0x7fffu + ((u >> 16) & 1u)) >> 16;  // RNE
  return (unsigned short)u;
}

__device__ __forceinline__ float fsig(float x) {
  return __builtin_amdgcn_rcpf(1.0f + __expf(-x));
}
__device__ __forceinline__ float ftanh_(float x) {
  return 2.0f * __builtin_amdgcn_rcpf(1.0f + __expf(-2.0f * x)) - 1.0f;
}

// Fused prep: one kernel, three block ranges (saves 2 launch gaps, lets the
// independent streaming jobs co-schedule across CUs).
//  b in [0,8192):      A[m][k] = k<1024 ? X : h0, bf16, 16 elems/thread
//  b in [8192,9216):   Bt[n][1024+k'] = W[n][k'], bf16, 16 elems/thread
//  b in [9216,13312):  Bt[n][k] = U[k][n] (k<1024), 32x32 LDS transpose
__global__ void prep(const float* __restrict__ X, const float* __restrict__ h0,
                     const float* __restrict__ W, const float* __restrict__ U,
                     unsigned short* __restrict__ A, unsigned short* __restrict__ Bt) {
  __shared__ float tile[32][33];
  int b = blockIdx.x;
  if (b < 9216) {
    const float* src;
    unsigned short* dst;
    if (b < 8192) {
      size_t idx = ((size_t)b * 256 + threadIdx.x) * 16;
      int m = (int)(idx >> 11);
      int k = (int)(idx & 2047);
      src = (k < 1024) ? (X + (size_t)m * 1024 + k)
                       : (h0 + (size_t)m * 1024 + (k - 1024));
      dst = A + idx;
    } else {
      size_t idx = ((size_t)(b - 8192) * 256 + threadIdx.x) * 16;  // over 4096*1024
      int n = (int)(idx >> 10);
      int k = (int)(idx & 1023);
      src = W + (size_t)n * 1024 + k;
      dst = Bt + (size_t)n * 2048 + 1024 + k;
    }
    float4 a = ((const float4*)src)[0];
    float4 bb = ((const float4*)src)[1];
    float4 c = ((const float4*)src)[2];
    float4 d = ((const float4*)src)[3];
    union { unsigned short u[16]; uint4 v[2]; } pk;
    pk.u[0] = f2bf(a.x); pk.u[1] = f2bf(a.y); pk.u[2] = f2bf(a.z); pk.u[3] = f2bf(a.w);
    pk.u[4] = f2bf(bb.x); pk.u[5] = f2bf(bb.y); pk.u[6] = f2bf(bb.z); pk.u[7] = f2bf(bb.w);
    pk.u[8]  = f2bf(c.x); pk.u[9]  = f2bf(c.y); pk.u[10] = f2bf(c.z); pk.u[11] = f2bf(c.w);
    pk.u[12] = f2bf(d.x); pk.u[13] = f2bf(d.y); pk.u[14] = f2bf(d.z); pk.u[15] = f2bf(d.w);
    *(uint4*)(dst) = pk.v[0];
    *(uint4*)(dst + 8) = pk.v[1];
  } else {
    int bb = b - 9216;                    // 4096 blocks: 128 n-tiles x 32 k-tiles
    int n0 = (bb & 127) * 32;
    int k0 = (bb >> 7) * 32;
    int tx = threadIdx.x & 31, ty = threadIdx.x >> 5;  // ty in [0,8)
    #pragma unroll
    for (int i = 0; i < 4; ++i)
      tile[ty + i * 8][tx] = U[(size_t)(k0 + ty + i * 8) * 4096 + n0 + tx];
    __syncthreads();
    int nrel = threadIdx.x >> 3;          // 0..31
    int kc = (threadIdx.x & 7) * 4;       // 0..28
    union { unsigned short u[4]; uint2 v8; } pk;
    #pragma unroll
    for (int i = 0; i < 4; ++i) pk.u[i] = f2bf(tile[kc + i][nrel]);
    *(uint2*)(Bt + (size_t)(n0 + nrel) * 2048 + k0 + kc) = pk.v8;
  }
}

// GEMM + fused LSTM epilogue.
// Grid: 1024 flat blocks (16 p-tiles x 64 m-tiles after XCD swizzle),
// 512 threads (8 waves: wm in [0,2) x wn in [0,4)); per-wave 128x64 output.
// LDS (dynamic, 128 KiB): A slots [4][256][32]bf16 @0, B slots @64KiB.
// 64B rows, 16B segs XOR-swizzled by (row>>1)&3 (both-sides involution:
// pre-swizzled global src for global_load_lds, swizzled ds_read addr).
// B LDS p-row rl holds physical n = ((rl>>4)&3)*1024 + j0 + (rl>>6)*16 + (rl&15)
// so acc[mi][ni] = gate ni of column j0 + wn*16 + cc.
// Per tile t: issue stage(t+3) -> ds_read frags for t+1 (alt reg set) ->
// 32 MFMA on tile t's regs (setprio) -> vmcnt(4) -> barrier.
__global__ __launch_bounds__(512, 2)
void lstm_gemm(const unsigned short* __restrict__ A, const unsigned short* __restrict__ Bt,
               const float* __restrict__ c0, float* __restrict__ out) {
  extern __shared__ char smem[];  // 131072 bytes
  const int tid = threadIdx.x;
  const int wave = tid >> 6, lane = tid & 63;
  const int q = lane >> 4, cc = lane & 15;
  const int wm = wave >> 2, wn = wave & 3;

  // T1: bijective XCD swizzle (nwg=1024 % 8 == 0).
  const int bid = blockIdx.x;
  const int swz = (bid & 7) * 128 + (bid >> 3);
  const int m0 = (swz >> 4) * 256;
  const int j0 = (swz & 15) * 64;

  // Staging source offsets (bytes/lane): lane l covers LDS row
  // u*128 + wave*16 + (l>>2), 16B seg (l&3) pre-XOR'd with row bits 1-2.
  const int srow = lane >> 2;
  const int sseg = (lane & 3) ^ ((lane >> 3) & 3);
  uint32_t aoff[2], boff[2];
  #pragma unroll
  for (int u = 0; u < 2; ++u) {
    int rl = u * 128 + wave * 16 + srow;     // LDS row 0..255
    aoff[u] = (((uint32_t)(m0 + rl) << 11) + (uint32_t)(sseg * 8)) * 2u;
    int n = (((rl >> 4) & 3) << 10) + j0 + ((rl >> 6) << 4) + (rl & 15);
    boff[u] = (((uint32_t)n << 11) + (uint32_t)(sseg * 8)) * 2u;
  }
  const char* Ab = (const char*)A;
  const char* Bb = (const char*)Bt;

  auto stageAB = [&](int tt) {
    const int slot = tt & 3;
    #pragma unroll
    for (int u = 0; u < 2; ++u) {
      uintptr_t l = (uintptr_t)(smem + slot * 16384 + u * 8192 + wave * 1024);
      __builtin_amdgcn_global_load_lds(
          (const __attribute__((address_space(1))) void*)(uintptr_t)(Ab + (aoff[u] + (uint32_t)tt * 64u)),
          (__attribute__((address_space(3))) void*)(uint32_t)l, 16, 0, 0);
    }
    #pragma unroll
    for (int u = 0; u < 2; ++u) {
      uintptr_t l = (uintptr_t)(smem + 65536 + slot * 16384 + u * 8192 + wave * 1024);
      __builtin_amdgcn_global_load_lds(
          (const __attribute__((address_space(1))) void*)(uintptr_t)(Bb + (boff[u] + (uint32_t)tt * 64u)),
          (__attribute__((address_space(3))) void*)(uint32_t)l, 16, 0, 0);
    }
  };

  f32x4 acc[8][4];
  #pragma unroll
  for (int a = 0; a < 8; ++a)
    #pragma unroll
    for (int b = 0; b < 4; ++b)
      acc[a][b] = f32x4{0.f, 0.f, 0.f, 0.f};

  // Frag-read base offsets (seg-swizzled by row bits 1-2, which come from cc).
  const uint32_t swzq = (uint32_t)((q ^ ((cc >> 1) & 3)) * 16);
  const uint32_t aRd = (uint32_t)((wm * 128 + cc) * 64) + swzq;
  const uint32_t bRd = 65536u + (uint32_t)((wn * 64 + cc) * 64) + swzq;

  auto readFrags = [&](bf16x8 (&fa)[8], bf16x8 (&fb)[4], int slot) {
    const char* sb = smem + slot * 16384;
    #pragma unroll
    for (int mi = 0; mi < 8; ++mi) fa[mi] = *(const bf16x8*)(sb + aRd + mi * 1024);
    #pragma unroll
    for (int ni = 0; ni < 4; ++ni) fb[ni] = *(const bf16x8*)(sb + bRd + ni * 1024);
  };
  auto domfma = [&](bf16x8 (&fa)[8], bf16x8 (&fb)[4]) {
    __builtin_amdgcn_s_setprio(1);
    #pragma unroll
    for (int mi = 0; mi < 8; ++mi)
      #pragma unroll
      for (int ni = 0; ni < 4; ++ni)
        acc[mi][ni] = __builtin_amdgcn_mfma_f32_16x16x32_bf16(fa[mi], fb[ni], acc[mi][ni], 0, 0, 0);
    __builtin_amdgcn_s_setprio(0);
  };

  // Prologue: stage tiles 0,1,2; force 0,1 landed (tile 2's 4 stay in
  // flight); barrier publishes. Pre-read tile 0's frags.
  stageAB(0); stageAB(1); stageAB(2);
  asm volatile("s_waitcnt vmcnt(4)" ::: "memory");
  __builtin_amdgcn_s_barrier();

  bf16x8 a0[8], b0[4], a1[8], b1[4];
  readFrags(a0, b0, 0);

  // Main loop, 2x unrolled for static frag-buffer indexing. Steady state:
  // start of tile t has tiles <=t+1 published, t+2 in flight (4 loads).
  for (int t = 0; t < NT - 4; t += 2) {
    // even tile t: compute (a0,b0), read (a1,b1) <- t+1
    stageAB(t + 3);
    readFrags(a1, b1, (t + 1) & 3);
    domfma(a0, b0);
    asm volatile("s_waitcnt vmcnt(4)" ::: "memory");  // t+2 landed
    __builtin_amdgcn_s_barrier();
    // odd tile t+1: compute (a1,b1), read (a0,b0) <- t+2
    stageAB(t + 4);
    readFrags(a0, b0, (t + 2) & 3);
    domfma(a1, b1);
    asm volatile("s_waitcnt vmcnt(4)" ::: "memory");  // t+3 landed
    __builtin_amdgcn_s_barrier();
  }
  // t=60: stage(63); read 61; mfma 60; vmcnt(4) [62 landed]; barrier
  stageAB(63);
  readFrags(a1, b1, 61 & 3);
  domfma(a0, b0);
  asm volatile("s_waitcnt vmcnt(4)" ::: "memory");
  __builtin_amdgcn_s_barrier();
  // t=61: read 62; mfma 61; vmcnt(0) [63 landed]; barrier
  readFrags(a0, b0, 62 & 3);
  domfma(a1, b1);
  asm volatile("s_waitcnt vmcnt(0)" ::: "memory");
  __builtin_amdgcn_s_barrier();
  // t=62: read 63; mfma 62 (no more LDS writes -> no wait/barrier)
  readFrags(a1, b1, 63 & 3);
  domfma(a0, b0);
  // t=63: mfma 63
  domfma(a1, b1);

  // Register-local fused epilogue: acc[mi][0..3] = i,f,g,o of (grow, gj).
  // C-layout: col = lane&15 (= cc), row = q*4 + r.
  const int gj = j0 + wn * 16 + cc;
  #pragma unroll
  for (int mi = 0; mi < 8; ++mi) {
    #pragma unroll
    for (int r = 0; r < 4; ++r) {
      int grow = m0 + wm * 128 + mi * 16 + q * 4 + r;
      float iv = fsig(acc[mi][0][r]);
      float fv = fsig(acc[mi][1][r]);
      float gv = ftanh_(acc[mi][2][r]);
      float ov = fsig(acc[mi][3][r]);
      float c0v = c0[(size_t)grow * DH + gj];
      float cv = fv * c0v + iv * gv;
      float hv = ov * ftanh_(cv);
      out[(size_t)grow * DH + gj] = hv;
      out[HC_ELEMS + (size_t)grow * DH + gj] = cv;
    }
  }
}

extern "C" void kernel_launch(void* const* d_in, const int* in_sizes, int n_in,
                              void* d_out, int out_size, void* d_ws, size_t ws_size,
                              hipStream_t stream) {
  const float* X  = (const float*)d_in[0];
  const float* h0 = (const float*)d_in[1];
  const float* c0 = (const float*)d_in[2];
  const float* U  = (const float*)d_in[3];
  const float* W  = (const float*)d_in[4];
  float* out = (float*)d_out;

  // ws layout: A_bf16 (16384x2048, 64MB) | Bt_bf16 (4096x2048, 16MB) = 80MB
  unsigned short* Abf = (unsigned short*)d_ws;
  unsigned short* Bt  = Abf + 33554432ull;

  static bool attr_set = false;
  if (!attr_set) {
    (void)hipFuncSetAttribute(reinterpret_cast<const void*>(lstm_gemm),
                              hipFuncAttributeMaxDynamicSharedMemorySize, 131072);
    attr_set = true;
  }

  prep<<<13312, 256, 0, stream>>>(X, h0, W, U, Abf, Bt);
  lstm_gemm<<<1024, 512, 131072, stream>>>(Abf, Bt, c0, out);
}

// Round 5
// 535.029 us; speedup vs baseline: 1.0214x; 1.0214x over previous
//
#include <hip/hip_runtime.h>
#include <hip/hip_bf16.h>
#include <stdint.h>

// LSTM cell: gates = [X|h0](16384x2048) @ Bt^T(2048x4096), fused epilogue.
// bf16 MFMA 16x16x32, 256x256 tile, 8 waves, BK=32, 4-deep LDS slots.
// R2: register-level fragment double-buffer (frags for tile t+1 read during
// tile t's MFMA burst; zero lgkm dependency between reads and MFMAs).
// R4: sched_group_barrier pins per-tile emission to {4 VMEM} then
// 4x{3 DS_READ, 8 MFMA} so the independent ds_reads are NOT sunk below the
// MFMA burst -> LDS pipe (~1152cyc/CU/tile) and matrix pipe (~1242cyc)
// co-run instead of alternating (R2 counters showed serial-sum timing).
// setprio removed (null on lockstep GEMM per m190; avoids fencing the
// scheduler away from the group pattern).
// Gate-interleaved p-space so acc[mi][0..3] = gates i,f,g,o of ONE output
// column in the SAME lane -> epilogue is pure register math.

typedef __bf16 bf16x8 __attribute__((ext_vector_type(8)));
typedef float f32x4 __attribute__((ext_vector_type(4)));

#define B_ROWS 16384
#define KDIM 2048
#define DH 1024
#define HC_ELEMS 16777216ull  // 16384*1024
#define NT 64                 // K-tiles of BK=32

__device__ __forceinline__ unsigned short f2bf(float f) {
  unsigned u = __float_as_uint(f);
  u = (u + 0x7fffu + ((u >> 16) & 1u)) >> 16;  // RNE
  return (unsigned short)u;
}

__device__ __forceinline__ float fsig(float x) {
  return __builtin_amdgcn_rcpf(1.0f + __expf(-x));
}
__device__ __forceinline__ float ftanh_(float x) {
  return 2.0f * __builtin_amdgcn_rcpf(1.0f + __expf(-2.0f * x)) - 1.0f;
}

// Fused prep: one kernel, three block ranges.
//  b in [0,8192):      A[m][k] = k<1024 ? X : h0, bf16, 16 elems/thread
//  b in [8192,9216):   Bt[n][1024+k'] = W[n][k'], bf16, 16 elems/thread
//  b in [9216,13312):  Bt[n][k] = U[k][n] (k<1024), 32x32 LDS transpose
__global__ void prep(const float* __restrict__ X, const float* __restrict__ h0,
                     const float* __restrict__ W, const float* __restrict__ U,
                     unsigned short* __restrict__ A, unsigned short* __restrict__ Bt) {
  __shared__ float tile[32][33];
  int b = blockIdx.x;
  if (b < 9216) {
    const float* src;
    unsigned short* dst;
    if (b < 8192) {
      size_t idx = ((size_t)b * 256 + threadIdx.x) * 16;
      int m = (int)(idx >> 11);
      int k = (int)(idx & 2047);
      src = (k < 1024) ? (X + (size_t)m * 1024 + k)
                       : (h0 + (size_t)m * 1024 + (k - 1024));
      dst = A + idx;
    } else {
      size_t idx = ((size_t)(b - 8192) * 256 + threadIdx.x) * 16;  // over 4096*1024
      int n = (int)(idx >> 10);
      int k = (int)(idx & 1023);
      src = W + (size_t)n * 1024 + k;
      dst = Bt + (size_t)n * 2048 + 1024 + k;
    }
    float4 a = ((const float4*)src)[0];
    float4 bb = ((const float4*)src)[1];
    float4 c = ((const float4*)src)[2];
    float4 d = ((const float4*)src)[3];
    union { unsigned short u[16]; uint4 v[2]; } pk;
    pk.u[0] = f2bf(a.x); pk.u[1] = f2bf(a.y); pk.u[2] = f2bf(a.z); pk.u[3] = f2bf(a.w);
    pk.u[4] = f2bf(bb.x); pk.u[5] = f2bf(bb.y); pk.u[6] = f2bf(bb.z); pk.u[7] = f2bf(bb.w);
    pk.u[8]  = f2bf(c.x); pk.u[9]  = f2bf(c.y); pk.u[10] = f2bf(c.z); pk.u[11] = f2bf(c.w);
    pk.u[12] = f2bf(d.x); pk.u[13] = f2bf(d.y); pk.u[14] = f2bf(d.z); pk.u[15] = f2bf(d.w);
    *(uint4*)(dst) = pk.v[0];
    *(uint4*)(dst + 8) = pk.v[1];
  } else {
    int bb = b - 9216;                    // 4096 blocks: 128 n-tiles x 32 k-tiles
    int n0 = (bb & 127) * 32;
    int k0 = (bb >> 7) * 32;
    int tx = threadIdx.x & 31, ty = threadIdx.x >> 5;  // ty in [0,8)
    #pragma unroll
    for (int i = 0; i < 4; ++i)
      tile[ty + i * 8][tx] = U[(size_t)(k0 + ty + i * 8) * 4096 + n0 + tx];
    __syncthreads();
    int nrel = threadIdx.x >> 3;          // 0..31
    int kc = (threadIdx.x & 7) * 4;       // 0..28
    union { unsigned short u[4]; uint2 v8; } pk;
    #pragma unroll
    for (int i = 0; i < 4; ++i) pk.u[i] = f2bf(tile[kc + i][nrel]);
    *(uint2*)(Bt + (size_t)(n0 + nrel) * 2048 + k0 + kc) = pk.v8;
  }
}

// Scheduling pin for one K-tile body (region delimited by s_barrier):
// emit the 4 global_load_lds first (HBM latency earliest), then interleave
// the 12 independent ds_read_b128 with the 32 MFMAs as 4x{3 DS, 8 MFMA}.
// Masks (LLVM SchedGroupMask): VMEM=0x10, DS_READ=0x100, MFMA=0x8.
__device__ __forceinline__ void pin_tile_schedule() {
  __builtin_amdgcn_sched_group_barrier(0x010, 4, 0);
  #pragma unroll
  for (int g = 0; g < 4; ++g) {
    __builtin_amdgcn_sched_group_barrier(0x100, 3, 0);
    __builtin_amdgcn_sched_group_barrier(0x008, 8, 0);
  }
}

// GEMM + fused LSTM epilogue.
// Grid: 1024 flat blocks (16 p-tiles x 64 m-tiles after XCD swizzle),
// 512 threads (8 waves: wm in [0,2) x wn in [0,4)); per-wave 128x64 output.
// LDS (dynamic, 128 KiB): A slots [4][256][32]bf16 @0, B slots @64KiB.
// 64B rows, 16B segs XOR-swizzled by (row>>1)&3 (both-sides involution:
// pre-swizzled global src for global_load_lds, swizzled ds_read addr).
// B LDS p-row rl holds physical n = ((rl>>4)&3)*1024 + j0 + (rl>>6)*16 + (rl&15)
// so acc[mi][ni] = gate ni of column j0 + wn*16 + cc.
// Per tile t: issue stage(t+3) -> ds_read frags for t+1 (alt reg set) ->
// 32 MFMA on tile t's regs -> vmcnt(4) -> barrier.
__global__ __launch_bounds__(512, 2)
void lstm_gemm(const unsigned short* __restrict__ A, const unsigned short* __restrict__ Bt,
               const float* __restrict__ c0, float* __restrict__ out) {
  extern __shared__ char smem[];  // 131072 bytes
  const int tid = threadIdx.x;
  const int wave = tid >> 6, lane = tid & 63;
  const int q = lane >> 4, cc = lane & 15;
  const int wm = wave >> 2, wn = wave & 3;

  // T1: bijective XCD swizzle (nwg=1024 % 8 == 0).
  const int bid = blockIdx.x;
  const int swz = (bid & 7) * 128 + (bid >> 3);
  const int m0 = (swz >> 4) * 256;
  const int j0 = (swz & 15) * 64;

  // Staging source offsets (bytes/lane): lane l covers LDS row
  // u*128 + wave*16 + (l>>2), 16B seg (l&3) pre-XOR'd with row bits 1-2.
  const int srow = lane >> 2;
  const int sseg = (lane & 3) ^ ((lane >> 3) & 3);
  uint32_t aoff[2], boff[2];
  #pragma unroll
  for (int u = 0; u < 2; ++u) {
    int rl = u * 128 + wave * 16 + srow;     // LDS row 0..255
    aoff[u] = (((uint32_t)(m0 + rl) << 11) + (uint32_t)(sseg * 8)) * 2u;
    int n = (((rl >> 4) & 3) << 10) + j0 + ((rl >> 6) << 4) + (rl & 15);
    boff[u] = (((uint32_t)n << 11) + (uint32_t)(sseg * 8)) * 2u;
  }
  const char* Ab = (const char*)A;
  const char* Bb = (const char*)Bt;

  auto stageAB = [&](int tt) {
    const int slot = tt & 3;
    #pragma unroll
    for (int u = 0; u < 2; ++u) {
      uintptr_t l = (uintptr_t)(smem + slot * 16384 + u * 8192 + wave * 1024);
      __builtin_amdgcn_global_load_lds(
          (const __attribute__((address_space(1))) void*)(uintptr_t)(Ab + (aoff[u] + (uint32_t)tt * 64u)),
          (__attribute__((address_space(3))) void*)(uint32_t)l, 16, 0, 0);
    }
    #pragma unroll
    for (int u = 0; u < 2; ++u) {
      uintptr_t l = (uintptr_t)(smem + 65536 + slot * 16384 + u * 8192 + wave * 1024);
      __builtin_amdgcn_global_load_lds(
          (const __attribute__((address_space(1))) void*)(uintptr_t)(Bb + (boff[u] + (uint32_t)tt * 64u)),
          (__attribute__((address_space(3))) void*)(uint32_t)l, 16, 0, 0);
    }
  };

  f32x4 acc[8][4];
  #pragma unroll
  for (int a = 0; a < 8; ++a)
    #pragma unroll
    for (int b = 0; b < 4; ++b)
      acc[a][b] = f32x4{0.f, 0.f, 0.f, 0.f};

  // Frag-read base offsets (seg-swizzled by row bits 1-2, which come from cc).
  const uint32_t swzq = (uint32_t)((q ^ ((cc >> 1) & 3)) * 16);
  const uint32_t aRd = (uint32_t)((wm * 128 + cc) * 64) + swzq;
  const uint32_t bRd = 65536u + (uint32_t)((wn * 64 + cc) * 64) + swzq;

  auto readFrags = [&](bf16x8 (&fa)[8], bf16x8 (&fb)[4], int slot) {
    const char* sb = smem + slot * 16384;
    #pragma unroll
    for (int mi = 0; mi < 8; ++mi) fa[mi] = *(const bf16x8*)(sb + aRd + mi * 1024);
    #pragma unroll
    for (int ni = 0; ni < 4; ++ni) fb[ni] = *(const bf16x8*)(sb + bRd + ni * 1024);
  };
  auto domfma = [&](bf16x8 (&fa)[8], bf16x8 (&fb)[4]) {
    #pragma unroll
    for (int mi = 0; mi < 8; ++mi)
      #pragma unroll
      for (int ni = 0; ni < 4; ++ni)
        acc[mi][ni] = __builtin_amdgcn_mfma_f32_16x16x32_bf16(fa[mi], fb[ni], acc[mi][ni], 0, 0, 0);
  };

  // Prologue: stage tiles 0,1,2; force 0,1 landed (tile 2's 4 stay in
  // flight); barrier publishes. Pre-read tile 0's frags.
  stageAB(0); stageAB(1); stageAB(2);
  asm volatile("s_waitcnt vmcnt(4)" ::: "memory");
  __builtin_amdgcn_s_barrier();

  bf16x8 a0[8], b0[4], a1[8], b1[4];
  readFrags(a0, b0, 0);

  // Main loop, 2x unrolled for static frag-buffer indexing. Steady state:
  // start of tile t has tiles <=t+1 published, t+2 in flight (4 loads).
  for (int t = 0; t < NT - 4; t += 2) {
    // even tile t: compute (a0,b0), read (a1,b1) <- t+1
    stageAB(t + 3);
    readFrags(a1, b1, (t + 1) & 3);
    domfma(a0, b0);
    pin_tile_schedule();
    asm volatile("s_waitcnt vmcnt(4)" ::: "memory");  // t+2 landed
    __builtin_amdgcn_s_barrier();
    // odd tile t+1: compute (a1,b1), read (a0,b0) <- t+2
    stageAB(t + 4);
    readFrags(a0, b0, (t + 2) & 3);
    domfma(a1, b1);
    pin_tile_schedule();
    asm volatile("s_waitcnt vmcnt(4)" ::: "memory");  // t+3 landed
    __builtin_amdgcn_s_barrier();
  }
  // t=60: stage(63); read 61; mfma 60; vmcnt(4) [62 landed]; barrier
  stageAB(63);
  readFrags(a1, b1, 61 & 3);
  domfma(a0, b0);
  pin_tile_schedule();
  asm volatile("s_waitcnt vmcnt(4)" ::: "memory");
  __builtin_amdgcn_s_barrier();
  // t=61: read 62; mfma 61; vmcnt(0) [63 landed]; barrier
  readFrags(a0, b0, 62 & 3);
  domfma(a1, b1);
  asm volatile("s_waitcnt vmcnt(0)" ::: "memory");
  __builtin_amdgcn_s_barrier();
  // t=62: read 63; mfma 62 (no more LDS writes -> no wait/barrier)
  readFrags(a1, b1, 63 & 3);
  domfma(a0, b0);
  // t=63: mfma 63
  domfma(a1, b1);

  // Register-local fused epilogue: acc[mi][0..3] = i,f,g,o of (grow, gj).
  // C-layout: col = lane&15 (= cc), row = q*4 + r.
  const int gj = j0 + wn * 16 + cc;
  #pragma unroll
  for (int mi = 0; mi < 8; ++mi) {
    #pragma unroll
    for (int r = 0; r < 4; ++r) {
      int grow = m0 + wm * 128 + mi * 16 + q * 4 + r;
      float iv = fsig(acc[mi][0][r]);
      float fv = fsig(acc[mi][1][r]);
      float gv = ftanh_(acc[mi][2][r]);
      float ov = fsig(acc[mi][3][r]);
      float c0v = c0[(size_t)grow * DH + gj];
      float cv = fv * c0v + iv * gv;
      float hv = ov * ftanh_(cv);
      out[(size_t)grow * DH + gj] = hv;
      out[HC_ELEMS + (size_t)grow * DH + gj] = cv;
    }
  }
}

extern "C" void kernel_launch(void* const* d_in, const int* in_sizes, int n_in,
                              void* d_out, int out_size, void* d_ws, size_t ws_size,
                              hipStream_t stream) {
  const float* X  = (const float*)d_in[0];
  const float* h0 = (const float*)d_in[1];
  const float* c0 = (const float*)d_in[2];
  const float* U  = (const float*)d_in[3];
  const float* W  = (const float*)d_in[4];
  float* out = (float*)d_out;

  // ws layout: A_bf16 (16384x2048, 64MB) | Bt_bf16 (4096x2048, 16MB) = 80MB
  unsigned short* Abf = (unsigned short*)d_ws;
  unsigned short* Bt  = Abf + 33554432ull;

  static bool attr_set = false;
  if (!attr_set) {
    (void)hipFuncSetAttribute(reinterpret_cast<const void*>(lstm_gemm),
                              hipFuncAttributeMaxDynamicSharedMemorySize, 131072);
    attr_set = true;
  }

  prep<<<13312, 256, 0, stream>>>(X, h0, W, U, Abf, Bt);
  lstm_gemm<<<1024, 512, 131072, stream>>>(Abf, Bt, c0, out);
}

// Round 7
// 526.458 us; speedup vs baseline: 1.0381x; 1.0163x over previous
//
#include <hip/hip_runtime.h>
#include <hip/hip_bf16.h>
#include <stdint.h>

// LSTM cell: gates = [X|h0](16384x2048) @ Bt^T(2048x4096), fused epilogue.
// bf16 MFMA 16x16x32, 256x256 tile, 8 waves, BK=32, 4-deep LDS slots.
// R6: m201-style phase discipline on the PROVEN R2 geometry/ledger.
// Per K-tile, 2 phases: {8 ds_reads ; stage 2 gloads ; [vmcnt(4)] ; barrier ;
// lgkmcnt(0)+sched_barrier ; setprio(1) 16 MFMA setprio(0) ; barrier}.
// Whole-tile vm ledger (R5's half-tile gating raced): distance-2 staging,
// vmcnt(4) once per tile forces tile t+1 landed, keeps t+2's 4 loads in
// flight across all barriers (never drains). Same-phase read->consume with
// per-wave lgkm gate = the wave-stagger mechanism (in-order LDS queue
// releases waves one by one into the matrix pipe).
// Gate-interleaved p-space: acc[mi][0..3] = gates i,f,g,o of ONE output
// column in the SAME lane -> epilogue is pure register math.

typedef __bf16 bf16x8 __attribute__((ext_vector_type(8)));
typedef float f32x4 __attribute__((ext_vector_type(4)));

#define B_ROWS 16384
#define KDIM 2048
#define DH 1024
#define HC_ELEMS 16777216ull  // 16384*1024
#define NT 64                 // K-tiles of BK=32

__device__ __forceinline__ unsigned short f2bf(float f) {
  unsigned u = __float_as_uint(f);
  u = (u + 0x7fffu + ((u >> 16) & 1u)) >> 16;  // RNE
  return (unsigned short)u;
}

__device__ __forceinline__ float fsig(float x) {
  return __builtin_amdgcn_rcpf(1.0f + __expf(-x));
}
__device__ __forceinline__ float ftanh_(float x) {
  return 2.0f * __builtin_amdgcn_rcpf(1.0f + __expf(-2.0f * x)) - 1.0f;
}

#define BAR __builtin_amdgcn_s_barrier()
#define LGKM0 do { asm volatile("s_waitcnt lgkmcnt(0)" ::: "memory"); \
                   __builtin_amdgcn_sched_barrier(0); } while (0)

// Fused prep: one kernel, three block ranges.
//  b in [0,8192):      A[m][k] = k<1024 ? X : h0, bf16, 16 elems/thread
//  b in [8192,9216):   Bt[n][1024+k'] = W[n][k'], bf16, 16 elems/thread
//  b in [9216,13312):  Bt[n][k] = U[k][n] (k<1024), 32x32 LDS transpose
__global__ void prep(const float* __restrict__ X, const float* __restrict__ h0,
                     const float* __restrict__ W, const float* __restrict__ U,
                     unsigned short* __restrict__ A, unsigned short* __restrict__ Bt) {
  __shared__ float tile[32][33];
  int b = blockIdx.x;
  if (b < 9216) {
    const float* src;
    unsigned short* dst;
    if (b < 8192) {
      size_t idx = ((size_t)b * 256 + threadIdx.x) * 16;
      int m = (int)(idx >> 11);
      int k = (int)(idx & 2047);
      src = (k < 1024) ? (X + (size_t)m * 1024 + k)
                       : (h0 + (size_t)m * 1024 + (k - 1024));
      dst = A + idx;
    } else {
      size_t idx = ((size_t)(b - 8192) * 256 + threadIdx.x) * 16;  // over 4096*1024
      int n = (int)(idx >> 10);
      int k = (int)(idx & 1023);
      src = W + (size_t)n * 1024 + k;
      dst = Bt + (size_t)n * 2048 + 1024 + k;
    }
    float4 a = ((const float4*)src)[0];
    float4 bb = ((const float4*)src)[1];
    float4 c = ((const float4*)src)[2];
    float4 d = ((const float4*)src)[3];
    union { unsigned short u[16]; uint4 v[2]; } pk;
    pk.u[0] = f2bf(a.x); pk.u[1] = f2bf(a.y); pk.u[2] = f2bf(a.z); pk.u[3] = f2bf(a.w);
    pk.u[4] = f2bf(bb.x); pk.u[5] = f2bf(bb.y); pk.u[6] = f2bf(bb.z); pk.u[7] = f2bf(bb.w);
    pk.u[8]  = f2bf(c.x); pk.u[9]  = f2bf(c.y); pk.u[10] = f2bf(c.z); pk.u[11] = f2bf(c.w);
    pk.u[12] = f2bf(d.x); pk.u[13] = f2bf(d.y); pk.u[14] = f2bf(d.z); pk.u[15] = f2bf(d.w);
    *(uint4*)(dst) = pk.v[0];
    *(uint4*)(dst + 8) = pk.v[1];
  } else {
    int bb = b - 9216;                    // 4096 blocks: 128 n-tiles x 32 k-tiles
    int n0 = (bb & 127) * 32;
    int k0 = (bb >> 7) * 32;
    int tx = threadIdx.x & 31, ty = threadIdx.x >> 5;  // ty in [0,8)
    #pragma unroll
    for (int i = 0; i < 4; ++i)
      tile[ty + i * 8][tx] = U[(size_t)(k0 + ty + i * 8) * 4096 + n0 + tx];
    __syncthreads();
    int nrel = threadIdx.x >> 3;          // 0..31
    int kc = (threadIdx.x & 7) * 4;       // 0..28
    union { unsigned short u[4]; uint2 v8; } pk;
    #pragma unroll
    for (int i = 0; i < 4; ++i) pk.u[i] = f2bf(tile[kc + i][nrel]);
    *(uint2*)(Bt + (size_t)(n0 + nrel) * 2048 + k0 + kc) = pk.v8;
  }
}

// GEMM + fused LSTM epilogue.
// Grid: 1024 flat blocks (16 p-tiles x 64 m-tiles after XCD swizzle),
// 512 threads (8 waves: wm in [0,2) x wn in [0,4)); per-wave 128x64 output.
// LDS (dynamic, 128 KiB): A slots [4][256][32]bf16 @0, B slots @64KiB.
// 64B rows, 16B segs XOR-swizzled by (row>>1)&3 (both-sides involution:
// pre-swizzled global src for global_load_lds, swizzled ds_read addr).
// B LDS p-row rl holds physical n = ((rl>>4)&3)*1024 + j0 + (rl>>6)*16 + (rl&15)
// so acc[mi][ni] = gate ni of column j0 + wn*16 + cc.
__global__ __launch_bounds__(512, 2)
void lstm_gemm(const unsigned short* __restrict__ A, const unsigned short* __restrict__ Bt,
               const float* __restrict__ c0, float* __restrict__ out) {
  extern __shared__ char smem[];  // 131072 bytes
  const int tid = threadIdx.x;
  const int wave = tid >> 6, lane = tid & 63;
  const int q = lane >> 4, cc = lane & 15;
  const int wm = wave >> 2, wn = wave & 3;

  // T1: bijective XCD swizzle (nwg=1024 % 8 == 0).
  const int bid = blockIdx.x;
  const int swz = (bid & 7) * 128 + (bid >> 3);
  const int m0 = (swz >> 4) * 256;
  const int j0 = (swz & 15) * 64;

  // Staging source offsets (bytes/lane): lane l covers LDS row
  // u*128 + wave*16 + (l>>2), 16B seg (l&3) pre-XOR'd with row bits 1-2.
  const int srow = lane >> 2;
  const int sseg = (lane & 3) ^ ((lane >> 3) & 3);
  uint32_t aoff[2], boff[2];
  #pragma unroll
  for (int u = 0; u < 2; ++u) {
    int rl = u * 128 + wave * 16 + srow;     // LDS row 0..255
    aoff[u] = (((uint32_t)(m0 + rl) << 11) + (uint32_t)(sseg * 8)) * 2u;
    int n = (((rl >> 4) & 3) << 10) + j0 + ((rl >> 6) << 4) + (rl & 15);
    boff[u] = (((uint32_t)n << 11) + (uint32_t)(sseg * 8)) * 2u;
  }
  const char* Ab = (const char*)A;
  const char* Bb = (const char*)Bt;

  auto stageA = [&](int tt) {
    const int slot = tt & 3;
    #pragma unroll
    for (int u = 0; u < 2; ++u) {
      uintptr_t l = (uintptr_t)(smem + slot * 16384 + u * 8192 + wave * 1024);
      __builtin_amdgcn_global_load_lds(
          (const __attribute__((address_space(1))) void*)(uintptr_t)(Ab + (aoff[u] + (uint32_t)tt * 64u)),
          (__attribute__((address_space(3))) void*)(uint32_t)l, 16, 0, 0);
    }
  };
  auto stageB = [&](int tt) {
    const int slot = tt & 3;
    #pragma unroll
    for (int u = 0; u < 2; ++u) {
      uintptr_t l = (uintptr_t)(smem + 65536 + slot * 16384 + u * 8192 + wave * 1024);
      __builtin_amdgcn_global_load_lds(
          (const __attribute__((address_space(1))) void*)(uintptr_t)(Bb + (boff[u] + (uint32_t)tt * 64u)),
          (__attribute__((address_space(3))) void*)(uint32_t)l, 16, 0, 0);
    }
  };

  f32x4 acc[8][4];
  #pragma unroll
  for (int a = 0; a < 8; ++a)
    #pragma unroll
    for (int b = 0; b < 4; ++b)
      acc[a][b] = f32x4{0.f, 0.f, 0.f, 0.f};

  // Frag-read base offsets (seg-swizzled by row bits 1-2, which come from cc).
  const uint32_t swzq = (uint32_t)((q ^ ((cc >> 1) & 3)) * 16);
  const uint32_t aRd = (uint32_t)((wm * 128 + cc) * 64) + swzq;
  const uint32_t bRd = 65536u + (uint32_t)((wn * 64 + cc) * 64) + swzq;

  bf16x8 afLo[4], afHi[4], bfr[4];

  // Prologue: stage tiles 0,1 (8 loads/wave); vmcnt(4) -> tile 0 landed,
  // tile 1's 4 stay in flight. Barrier publishes tile 0 workgroup-wide.
  stageA(0); stageB(0);
  stageA(1); stageB(1);
  asm volatile("s_waitcnt vmcnt(4)" ::: "memory");
  BAR;

  // Steady state: at start of tile t, buf[t] landed, t+1's 4 loads in flight.
  for (int t = 0; t < NT - 2; ++t) {
    const char* sb = smem + (t & 3) * 16384;
    // ---- phase A: A-lo frags + all B frags; stage A(t+2); 16 MFMA ----
    #pragma unroll
    for (int mi = 0; mi < 4; ++mi) afLo[mi] = *(const bf16x8*)(sb + aRd + mi * 1024);
    #pragma unroll
    for (int ni = 0; ni < 4; ++ni) bfr[ni] = *(const bf16x8*)(sb + bRd + ni * 1024);
    stageA(t + 2);
    BAR; LGKM0;
    __builtin_amdgcn_s_setprio(1);
    #pragma unroll
    for (int mi = 0; mi < 4; ++mi)
      #pragma unroll
      for (int ni = 0; ni < 4; ++ni)
        acc[mi][ni] = __builtin_amdgcn_mfma_f32_16x16x32_bf16(afLo[mi], bfr[ni], acc[mi][ni], 0, 0, 0);
    __builtin_amdgcn_s_setprio(0);
    BAR;
    // ---- phase B: A-hi frags; stage B(t+2); vmcnt(4); 16 MFMA ----
    #pragma unroll
    for (int mi = 0; mi < 4; ++mi) afHi[mi] = *(const bf16x8*)(sb + aRd + 4096 + mi * 1024);
    stageB(t + 2);
    asm volatile("s_waitcnt vmcnt(4)" ::: "memory");  // t+1 landed; t+2 in flight
    BAR; LGKM0;
    __builtin_amdgcn_s_setprio(1);
    #pragma unroll
    for (int mi = 0; mi < 4; ++mi)
      #pragma unroll
      for (int ni = 0; ni < 4; ++ni)
        acc[4 + mi][ni] = __builtin_amdgcn_mfma_f32_16x16x32_bf16(afHi[mi], bfr[ni], acc[4 + mi][ni], 0, 0, 0);
    __builtin_amdgcn_s_setprio(0);
    BAR;
  }
  // Tile NT-2: no staging; vmcnt(0) drains tile NT-1's 4 loads.
  {
    const char* sb = smem + ((NT - 2) & 3) * 16384;
    #pragma unroll
    for (int mi = 0; mi < 4; ++mi) afLo[mi] = *(const bf16x8*)(sb + aRd + mi * 1024);
    #pragma unroll
    for (int ni = 0; ni < 4; ++ni) bfr[ni] = *(const bf16x8*)(sb + bRd + ni * 1024);
    BAR; LGKM0;
    __builtin_amdgcn_s_setprio(1);
    #pragma unroll
    for (int mi = 0; mi < 4; ++mi)
      #pragma unroll
      for (int ni = 0; ni < 4; ++ni)
        acc[mi][ni] = __builtin_amdgcn_mfma_f32_16x16x32_bf16(afLo[mi], bfr[ni], acc[mi][ni], 0, 0, 0);
    __builtin_amdgcn_s_setprio(0);
    BAR;
    #pragma unroll
    for (int mi = 0; mi < 4; ++mi) afHi[mi] = *(const bf16x8*)(sb + aRd + 4096 + mi * 1024);
    asm volatile("s_waitcnt vmcnt(0)" ::: "memory");  // tile NT-1 landed
    BAR; LGKM0;
    __builtin_amdgcn_s_setprio(1);
    #pragma unroll
    for (int mi = 0; mi < 4; ++mi)
      #pragma unroll
      for (int ni = 0; ni < 4; ++ni)
        acc[4 + mi][ni] = __builtin_amdgcn_mfma_f32_16x16x32_bf16(afHi[mi], bfr[ni], acc[4 + mi][ni], 0, 0, 0);
    __builtin_amdgcn_s_setprio(0);
    BAR;
  }
  // Tile NT-1: reads only (buf landed and published); per-wave lgkm gates.
  {
    const char* sb = smem + ((NT - 1) & 3) * 16384;
    #pragma unroll
    for (int mi = 0; mi < 4; ++mi) afLo[mi] = *(const bf16x8*)(sb + aRd + mi * 1024);
    #pragma unroll
    for (int ni = 0; ni < 4; ++ni) bfr[ni] = *(const bf16x8*)(sb + bRd + ni * 1024);
    LGKM0;
    __builtin_amdgcn_s_setprio(1);
    #pragma unroll
    for (int mi = 0; mi < 4; ++mi)
      #pragma unroll
      for (int ni = 0; ni < 4; ++ni)
        acc[mi][ni] = __builtin_amdgcn_mfma_f32_16x16x32_bf16(afLo[mi], bfr[ni], acc[mi][ni], 0, 0, 0);
    __builtin_amdgcn_s_setprio(0);
    #pragma unroll
    for (int mi = 0; mi < 4; ++mi) afHi[mi] = *(const bf16x8*)(sb + aRd + 4096 + mi * 1024);
    LGKM0;
    __builtin_amdgcn_s_setprio(1);
    #pragma unroll
    for (int mi = 0; mi < 4; ++mi)
      #pragma unroll
      for (int ni = 0; ni < 4; ++ni)
        acc[4 + mi][ni] = __builtin_amdgcn_mfma_f32_16x16x32_bf16(afHi[mi], bfr[ni], acc[4 + mi][ni], 0, 0, 0);
    __builtin_amdgcn_s_setprio(0);
  }

  // Register-local fused epilogue: acc[mi][0..3] = i,f,g,o of (grow, gj).
  // C-layout: col = lane&15 (= cc), row = q*4 + r.
  const int gj = j0 + wn * 16 + cc;
  #pragma unroll
  for (int mi = 0; mi < 8; ++mi) {
    #pragma unroll
    for (int r = 0; r < 4; ++r) {
      int grow = m0 + wm * 128 + mi * 16 + q * 4 + r;
      float iv = fsig(acc[mi][0][r]);
      float fv = fsig(acc[mi][1][r]);
      float gv = ftanh_(acc[mi][2][r]);
      float ov = fsig(acc[mi][3][r]);
      float c0v = c0[(size_t)grow * DH + gj];
      float cv = fv * c0v + iv * gv;
      float hv = ov * ftanh_(cv);
      out[(size_t)grow * DH + gj] = hv;
      out[HC_ELEMS + (size_t)grow * DH + gj] = cv;
    }
  }
}

extern "C" void kernel_launch(void* const* d_in, const int* in_sizes, int n_in,
                              void* d_out, int out_size, void* d_ws, size_t ws_size,
                              hipStream_t stream) {
  const float* X  = (const float*)d_in[0];
  const float* h0 = (const float*)d_in[1];
  const float* c0 = (const float*)d_in[2];
  const float* U  = (const float*)d_in[3];
  const float* W  = (const float*)d_in[4];
  float* out = (float*)d_out;

  // ws layout: A_bf16 (16384x2048, 64MB) | Bt_bf16 (4096x2048, 16MB) = 80MB
  unsigned short* Abf = (unsigned short*)d_ws;
  unsigned short* Bt  = Abf + 33554432ull;

  static bool attr_set = false;
  if (!attr_set) {
    (void)hipFuncSetAttribute(reinterpret_cast<const void*>(lstm_gemm),
                              hipFuncAttributeMaxDynamicSharedMemorySize, 131072);
    attr_set = true;
  }

  prep<<<13312, 256, 0, stream>>>(X, h0, W, U, Abf, Bt);
  lstm_gemm<<<1024, 512, 131072, stream>>>(Abf, Bt, c0, out);
}